// Round 3
// baseline (222.685 us; speedup 1.0000x reference)
//
#include <hip/hip_runtime.h>
#include <hip/hip_bf16.h>

typedef __attribute__((ext_vector_type(8))) short bf16x8;
typedef __attribute__((ext_vector_type(4))) float f32x4;
typedef __attribute__((ext_vector_type(4))) unsigned short us4;

__device__ __forceinline__ unsigned short f2bf(float f) {
    union { float f; unsigned u; } c; c.f = f;
    unsigned u = c.u;
    u += 0x7fffu + ((u >> 16) & 1u);   // RNE (no NaNs in this problem)
    return (unsigned short)(u >> 16);
}
__device__ __forceinline__ float bf2f(unsigned short h) {
    union { unsigned u; float f; } c; c.u = ((unsigned)h) << 16;
    return c.f;
}

// ---------------- Kernel 1: W -> WbT (bf16, transposed, [384][1024]) -------
__global__ __launch_bounds__(256) void wconv_kernel(
        const float* __restrict__ Wk, const float* __restrict__ Wq,
        const float* __restrict__ Wv, unsigned short* __restrict__ WbT) {
    int idx = blockIdx.x * 256 + threadIdx.x;     // 384*1024 total
    int n = idx >> 10, kk = idx & 1023;
    const float* W = (n < 128) ? Wk : (n < 256) ? Wq : Wv;
    int col = n & 127;
    WbT[idx] = f2bf(W[kk * 128 + col]);
}

// ---------------- Kernel 2: fused QKV projection GEMM ----------------------
// One pass over x. Tile: 64 rows x 384 cols, 512 threads (8 waves, each
// 64x48). K-step 32, reg-staged single-buffer pipeline (T14).
__global__ __launch_bounds__(512) void qkv_gemm_kernel(
        const float* __restrict__ x, const unsigned short* __restrict__ WbT,
        unsigned short* __restrict__ kw, unsigned short* __restrict__ qw,
        unsigned short* __restrict__ vTw) {
    __shared__ __align__(16) unsigned short Al[64 * 40];    // +8 pad
    __shared__ __align__(16) unsigned short Bl[384 * 40];   // +8 pad
    const int tid = threadIdx.x;
    const int m0 = blockIdx.x * 64;
    const int w = tid >> 6, l = tid & 63;
    const int l15 = l & 15, lh = l >> 4;

    f32x4 acc[4][3] = {};

    const int ar = tid >> 3, ac = (tid & 7) * 4;   // A: 4 fp32 per thread

    float4 aV;
    bf16x8 bV[3];

    // issue global loads for K-step k0 into regs
    auto issue = [&](int k0) {
        aV = *(const float4*)&x[(size_t)(m0 + ar) * 1024 + k0 + ac];
        for (int it = 0; it < 3; ++it) {
            int idx = it * 512 + tid;
            bV[it] = *(const bf16x8*)&WbT[(size_t)(idx >> 2) * 1024 + k0 + (idx & 3) * 8];
        }
    };

    issue(0);
    for (int t = 0; t < 32; ++t) {
        // write staged regs -> LDS
        {
            union { unsigned short u[4]; us4 v; } pk;
            pk.u[0] = f2bf(aV.x); pk.u[1] = f2bf(aV.y);
            pk.u[2] = f2bf(aV.z); pk.u[3] = f2bf(aV.w);
            *(us4*)&Al[ar * 40 + ac] = pk.v;
            for (int it = 0; it < 3; ++it) {
                int idx = it * 512 + tid;
                *(bf16x8*)&Bl[(idx >> 2) * 40 + (idx & 3) * 8] = bV[it];
            }
        }
        __syncthreads();                       // tile visible
        if (t + 1 < 32) issue((t + 1) * 32);   // overlap next loads w/ compute
        bf16x8 a[4], bb[3];
        for (int mi = 0; mi < 4; ++mi)
            a[mi] = *(bf16x8*)&Al[(mi * 16 + l15) * 40 + lh * 8];
        for (int ni = 0; ni < 3; ++ni)
            bb[ni] = *(bf16x8*)&Bl[(w * 48 + ni * 16 + l15) * 40 + lh * 8];
        for (int mi = 0; mi < 4; ++mi)
            for (int ni = 0; ni < 3; ++ni)
                acc[mi][ni] = __builtin_amdgcn_mfma_f32_16x16x32_bf16(
                        a[mi], bb[ni], acc[mi][ni], 0, 0, 0);
        __syncthreads();                       // readers done, buffer reusable
    }

    // epilogue: C/D layout col = l&15, row = (l>>4)*4 + i
    for (int mi = 0; mi < 4; ++mi)
        for (int ni = 0; ni < 3; ++ni) {
            int col = w * 48 + ni * 16 + l15;  // 0..383, 16-range never crosses 128
            int sect = col >> 7, cc = col & 127;
            if (sect < 2) {
                unsigned short* dst = (sect == 0) ? kw : qw;
                for (int i = 0; i < 4; ++i) {
                    int row = m0 + mi * 16 + lh * 4 + i;
                    dst[(size_t)row * 128 + cc] = f2bf(acc[mi][ni][i]);
                }
            } else {
                int trow0 = m0 + mi * 16 + lh * 4;
                int b = trow0 >> 12, t0 = trow0 & 4095;
                union { unsigned short u[4]; us4 v; } pk;
                for (int i = 0; i < 4; ++i) pk.u[i] = f2bf(acc[mi][ni][i]);
                *(us4*)&vTw[((size_t)(b * 128 + cc)) * 4096 + t0] = pk.v;
            }
        }
}

// ---------------- Kernel 3: split-KV flash attention (no K/V staging) ------
// Chunk = 8 kv-tiles (512 positions). Per batch 288 chunks; grid (288, 4).
// No __syncthreads in the KV loop: B-frags read direct from global (L1/L2).
__global__ __launch_bounds__(256) void attn_kernel(
        const unsigned short* __restrict__ kw, const unsigned short* __restrict__ qw,
        const unsigned short* __restrict__ vTw,
        unsigned short* __restrict__ pO, float* __restrict__ pML) {
    __shared__ __align__(16) unsigned short Pl[4][16 * 72]; // per-wave P, padded

    const int tid = threadIdx.x;
    const int b = blockIdx.y;
    const int cid = 287 - blockIdx.x;             // longest chunks first
    int j = 0;
    while (4 * (j + 1) * (j + 2) <= cid) ++j;     // group: qt in [8j, 8j+7], j+1 chunks
    int rem = cid - 4 * j * (j + 1);
    const int qt = 8 * j + rem / (j + 1);
    const int c  = rem % (j + 1);
    const int kt0 = c * 8;
    const int kt1 = min(kt0 + 8, qt + 1);

    const int w = tid >> 6, l = tid & 63;
    const int l15 = l & 15, lh = l >> 4;

    bf16x8 qa[4];
    {
        size_t grow = (size_t)b * 4096 + qt * 64 + w * 16 + l15;
        for (int cc = 0; cc < 4; ++cc)
            qa[cc] = *(const bf16x8*)&qw[grow * 128 + cc * 32 + lh * 8];
    }

    f32x4 o[8] = {};
    float m_[4], ls[4];
    for (int i = 0; i < 4; ++i) { m_[i] = -INFINITY; ls[i] = 0.f; }

    const unsigned short* kb0 = &kw[(size_t)b * 4096 * 128];
    const unsigned short* vb0 = &vTw[(size_t)b * 128 * 4096];

    for (int kt = kt0; kt < kt1; ++kt) {
        const int kv0 = kt * 64;
        // S = Q K^T; B-frag lanewise: K[kv0+ni*16+l15][cc*32+lh*8 ..+8]
        f32x4 s[4];
        __builtin_amdgcn_s_setprio(1);
        for (int ni = 0; ni < 4; ++ni) {
            s[ni] = (f32x4){0.f, 0.f, 0.f, 0.f};
            const unsigned short* kr = &kb0[(size_t)(kv0 + ni * 16 + l15) * 128 + lh * 8];
            for (int cc = 0; cc < 4; ++cc) {
                bf16x8 bk = *(const bf16x8*)(kr + cc * 32);
                s[ni] = __builtin_amdgcn_mfma_f32_16x16x32_bf16(qa[cc], bk, s[ni], 0, 0, 0);
            }
        }
        __builtin_amdgcn_s_setprio(0);
        // scale + causal mask (diag tile only)
        const bool diag = (kt == qt);
        for (int ni = 0; ni < 4; ++ni)
            for (int i = 0; i < 4; ++i) {
                float v = s[ni][i] * 0.03125f;      // C^-0.5 = 1024^-0.5
                bool masked = diag && (ni * 16 + l15 > w * 16 + lh * 4 + i);
                s[ni][i] = masked ? -INFINITY : v;
            }
        // online softmax; rows live on 16-lane groups (row = lh*4+i)
        float sc[4];
        for (int i = 0; i < 4; ++i) {
            float mx = fmaxf(fmaxf(s[0][i], s[1][i]), fmaxf(s[2][i], s[3][i]));
            for (int msk = 1; msk < 16; msk <<= 1) mx = fmaxf(mx, __shfl_xor(mx, msk));
            float mn = fmaxf(m_[i], mx);
            float e = __expf(m_[i] - mn);
            m_[i] = mn;
            float rs = 0.f;
            for (int ni = 0; ni < 4; ++ni) {
                float p = __expf(s[ni][i] - mn);
                s[ni][i] = p; rs += p;
            }
            for (int msk = 1; msk < 16; msk <<= 1) rs += __shfl_xor(rs, msk);
            ls[i] = ls[i] * e + rs;
            sc[i] = e;
        }
        for (int nd = 0; nd < 8; ++nd) {
            f32x4 t = o[nd];
            t[0] *= sc[0]; t[1] *= sc[1]; t[2] *= sc[2]; t[3] *= sc[3];
            o[nd] = t;
        }
        // P (C-layout) -> LDS (row-major, +8 pad), wave-local
        for (int ni = 0; ni < 4; ++ni)
            for (int i = 0; i < 4; ++i)
                Pl[w][(lh * 4 + i) * 72 + ni * 16 + l15] = f2bf(s[ni][i]);
        bf16x8 pa[2];
        for (int kc = 0; kc < 2; ++kc)
            pa[kc] = *(bf16x8*)&Pl[w][l15 * 72 + kc * 32 + lh * 8];
        // PV: B-frag lanewise: vT[nd*16+l15][kv0 + kc*32 + lh*8 ..+8]
        __builtin_amdgcn_s_setprio(1);
        for (int nd = 0; nd < 8; ++nd) {
            const unsigned short* vr = &vb0[(size_t)(nd * 16 + l15) * 4096 + kv0 + lh * 8];
            for (int kc = 0; kc < 2; ++kc) {
                bf16x8 bv = *(const bf16x8*)(vr + kc * 32);
                o[nd] = __builtin_amdgcn_mfma_f32_16x16x32_bf16(pa[kc], bv, o[nd], 0, 0, 0);
            }
        }
        __builtin_amdgcn_s_setprio(0);
    }

    // epilogue: unnormalized partial O (bf16) + m,l (f32), compact slot
    const int slot = b * 288 + cid;
    unsigned short* po = pO + (size_t)slot * 8192;
    for (int nd = 0; nd < 8; ++nd)
        for (int i = 0; i < 4; ++i)
            po[(w * 16 + lh * 4 + i) * 128 + nd * 16 + l15] = f2bf(o[nd][i]);
    if (l15 == 0) {
        float* pml = pML + (size_t)slot * 128;
        for (int i = 0; i < 4; ++i) {
            int row = w * 16 + lh * 4 + i;
            pml[row * 2]     = m_[i];
            pml[row * 2 + 1] = ls[i];
        }
    }
}

// ---------------- Kernel 4: combine partials (8 outputs/thread) ------------
__global__ __launch_bounds__(256) void combine_kernel(
        const unsigned short* __restrict__ pO, const float* __restrict__ pML,
        float* __restrict__ out) {
    int idx = blockIdx.x * 256 + threadIdx.x;     // B*T*16 = 262144 threads
    int row = idx >> 4, d8 = (idx & 15) * 8;
    int b = row >> 12, t = row & 4095;
    int qt = t >> 6, rowin = t & 63;
    int j = qt >> 3;
    int nch = j + 1;
    int base = b * 288 + 4 * j * (j + 1) + (qt - 8 * j) * (j + 1);

    float M = -INFINITY;
    for (int cc = 0; cc < nch; ++cc)
        M = fmaxf(M, pML[(size_t)(base + cc) * 128 + rowin * 2]);
    float den = 0.f;
    float num[8] = {0.f, 0.f, 0.f, 0.f, 0.f, 0.f, 0.f, 0.f};
    for (int cc = 0; cc < nch; ++cc) {
        const float* pml = &pML[(size_t)(base + cc) * 128 + rowin * 2];
        float wgt = __expf(pml[0] - M);
        den += wgt * pml[1];
        bf16x8 ov = *(const bf16x8*)&pO[(size_t)(base + cc) * 8192 + rowin * 128 + d8];
        for (int u = 0; u < 8; ++u)
            num[u] += wgt * bf2f((unsigned short)ov[u]);
    }
    float inv = 1.f / den;
    for (int u = 0; u < 8; ++u)
        out[(size_t)row * 128 + d8 + u] = num[u] * inv;
}

// ---------------------------------------------------------------------------
extern "C" void kernel_launch(void* const* d_in, const int* in_sizes, int n_in,
                              void* d_out, int out_size, void* d_ws, size_t ws_size,
                              hipStream_t stream) {
    const float* x  = (const float*)d_in[0];
    const float* Wk = (const float*)d_in[1];
    const float* Wq = (const float*)d_in[2];
    const float* Wv = (const float*)d_in[3];
    float* out = (float*)d_out;

    // ws layout (bytes):
    //   WbT 786432 | k 4194304 | q 4194304 | vT 4194304
    //   pO 1152*16384 = 18874368 | pML 1152*512 = 589824   (total ~32.8 MB)
    char* ws = (char*)d_ws;
    unsigned short* WbT = (unsigned short*)(ws);
    unsigned short* kw  = (unsigned short*)(ws + 786432);
    unsigned short* qw  = (unsigned short*)(ws + 786432 + 4194304);
    unsigned short* vTw = (unsigned short*)(ws + 786432 + 2 * 4194304);
    unsigned short* pO  = (unsigned short*)(ws + 786432 + 3 * 4194304);
    float*          pML = (float*)(ws + 786432 + 3 * 4194304 + 18874368);

    wconv_kernel<<<1536, 256, 0, stream>>>(Wk, Wq, Wv, WbT);
    qkv_gemm_kernel<<<256, 512, 0, stream>>>(x, WbT, kw, qw, vTw);
    attn_kernel<<<dim3(288, 4), 256, 0, stream>>>(kw, qw, vTw, pO, pML);
    combine_kernel<<<1024, 256, 0, stream>>>(pO, pML, out);
}

// Round 4
// 116.111 us; speedup vs baseline: 1.9179x; 1.9179x over previous
//
#include <hip/hip_runtime.h>
#include <hip/hip_bf16.h>

typedef __attribute__((ext_vector_type(8))) short bf16x8;
typedef __attribute__((ext_vector_type(4))) float f32x4;
typedef __attribute__((ext_vector_type(4))) unsigned short us4;

__device__ __forceinline__ unsigned short f2bf(float f) {
    union { float f; unsigned u; } c; c.f = f;
    unsigned u = c.u;
    u += 0x7fffu + ((u >> 16) & 1u);   // RNE (no NaNs in this problem)
    return (unsigned short)(u >> 16);
}
__device__ __forceinline__ float bf2f(unsigned short h) {
    union { unsigned u; float f; } c; c.u = ((unsigned)h) << 16;
    return c.f;
}

// ---------------- Kernel 1: W -> WbT (bf16, transposed, [384][1024]) -------
__global__ __launch_bounds__(256) void wconv_kernel(
        const float* __restrict__ Wk, const float* __restrict__ Wq,
        const float* __restrict__ Wv, unsigned short* __restrict__ WbT) {
    int idx = blockIdx.x * 256 + threadIdx.x;     // 384*1024 total
    int n = idx >> 10, kk = idx & 1023;
    const float* W = (n < 128) ? Wk : (n < 256) ? Wq : Wv;
    int col = n & 127;
    WbT[idx] = f2bf(W[kk * 128 + col]);
}

// ---------------- Kernel 2: fused QKV projection GEMM ----------------------
// One pass over x. Tile: 64 rows x 384 cols, 512 threads (8 waves, each
// 64x48). K-step 32, reg-staged single-buffer pipeline (T14).
__global__ __launch_bounds__(512) void qkv_gemm_kernel(
        const float* __restrict__ x, const unsigned short* __restrict__ WbT,
        unsigned short* __restrict__ kw, unsigned short* __restrict__ qw,
        unsigned short* __restrict__ vTw) {
    __shared__ __align__(16) unsigned short Al[64 * 40];    // +8 pad
    __shared__ __align__(16) unsigned short Bl[384 * 40];   // +8 pad
    const int tid = threadIdx.x;
    const int m0 = blockIdx.x * 64;
    const int w = tid >> 6, l = tid & 63;
    const int l15 = l & 15, lh = l >> 4;

    f32x4 acc[4][3] = {};

    const int ar = tid >> 3, ac = (tid & 7) * 4;   // A: 4 fp32 per thread

    float4 aV;
    bf16x8 bV[3];

    auto issue = [&](int k0) {
        aV = *(const float4*)&x[(size_t)(m0 + ar) * 1024 + k0 + ac];
        for (int it = 0; it < 3; ++it) {
            int idx = it * 512 + tid;
            bV[it] = *(const bf16x8*)&WbT[(size_t)(idx >> 2) * 1024 + k0 + (idx & 3) * 8];
        }
    };

    issue(0);
    for (int t = 0; t < 32; ++t) {
        {
            union { unsigned short u[4]; us4 v; } pk;
            pk.u[0] = f2bf(aV.x); pk.u[1] = f2bf(aV.y);
            pk.u[2] = f2bf(aV.z); pk.u[3] = f2bf(aV.w);
            *(us4*)&Al[ar * 40 + ac] = pk.v;
            for (int it = 0; it < 3; ++it) {
                int idx = it * 512 + tid;
                *(bf16x8*)&Bl[(idx >> 2) * 40 + (idx & 3) * 8] = bV[it];
            }
        }
        __syncthreads();                       // tile visible
        if (t + 1 < 32) issue((t + 1) * 32);   // overlap next loads w/ compute
        bf16x8 a[4], bb[3];
        for (int mi = 0; mi < 4; ++mi)
            a[mi] = *(bf16x8*)&Al[(mi * 16 + l15) * 40 + lh * 8];
        for (int ni = 0; ni < 3; ++ni)
            bb[ni] = *(bf16x8*)&Bl[(w * 48 + ni * 16 + l15) * 40 + lh * 8];
        for (int mi = 0; mi < 4; ++mi)
            for (int ni = 0; ni < 3; ++ni)
                acc[mi][ni] = __builtin_amdgcn_mfma_f32_16x16x32_bf16(
                        a[mi], bb[ni], acc[mi][ni], 0, 0, 0);
        __syncthreads();                       // readers done, buffer reusable
    }

    for (int mi = 0; mi < 4; ++mi)
        for (int ni = 0; ni < 3; ++ni) {
            int col = w * 48 + ni * 16 + l15;  // 16-range never crosses 128
            int sect = col >> 7, cc = col & 127;
            if (sect < 2) {
                unsigned short* dst = (sect == 0) ? kw : qw;
                for (int i = 0; i < 4; ++i) {
                    int row = m0 + mi * 16 + lh * 4 + i;
                    dst[(size_t)row * 128 + cc] = f2bf(acc[mi][ni][i]);
                }
            } else {
                int trow0 = m0 + mi * 16 + lh * 4;
                int b = trow0 >> 12, t0 = trow0 & 4095;
                union { unsigned short u[4]; us4 v; } pk;
                for (int i = 0; i < 4; ++i) pk.u[i] = f2bf(acc[mi][ni][i]);
                *(us4*)&vTw[((size_t)(b * 128 + cc)) * 4096 + t0] = pk.v;
            }
        }
}

// ---------------- Kernel 3: split-KV flash attention -----------------------
// Chunk = 8 kv-tiles (512 positions); per batch 288 chunks; grid (288, 4).
// K/V staged in swizzled LDS; T14 async-stage (loads for t+1 issued after
// the tile-t barrier, landing during tile-t compute).
__global__ __launch_bounds__(256) void attn_kernel(
        const unsigned short* __restrict__ kw, const unsigned short* __restrict__ qw,
        const unsigned short* __restrict__ vTw,
        unsigned short* __restrict__ pO, float* __restrict__ pML) {
    __shared__ __align__(16) unsigned short Kl[64 * 128];   // [kv row][d], swizzled
    __shared__ __align__(16) unsigned short Vl[128 * 64];   // [d][kv], swizzled
    __shared__ __align__(16) unsigned short Pl[4][16 * 72]; // per-wave P, padded

    const int tid = threadIdx.x;
    const int b = blockIdx.y;
    const int cid = 287 - blockIdx.x;             // longest chunks first
    int j = 0;
    while (4 * (j + 1) * (j + 2) <= cid) ++j;     // qt in [8j,8j+7], j+1 chunks
    int rem = cid - 4 * j * (j + 1);
    const int qt = 8 * j + rem / (j + 1);
    const int c  = rem % (j + 1);
    const int kt0 = c * 8;
    const int kt1 = min(kt0 + 8, qt + 1);

    const int w = tid >> 6, l = tid & 63;
    const int l15 = l & 15, lh = l >> 4;

    bf16x8 qa[4];
    {
        size_t grow = (size_t)b * 4096 + qt * 64 + w * 16 + l15;
        for (int cc = 0; cc < 4; ++cc)
            qa[cc] = *(const bf16x8*)&qw[grow * 128 + cc * 32 + lh * 8];
    }

    f32x4 o[8] = {};
    float m_[4], ls[4];
    for (int i = 0; i < 4; ++i) { m_[i] = -INFINITY; ls[i] = 0.f; }

    const int kr_ = tid >> 4, ksl = tid & 15;     // K stage: 4 rows/thread
    const int vd_ = tid >> 3, vsl = tid & 7;      // V stage: 4 d-rows/thread
    bf16x8 kReg[4], vReg[4];
    auto issue = [&](int kt) {
        int kv0 = kt * 64;
        for (int it = 0; it < 4; ++it)
            kReg[it] = *(const bf16x8*)&kw[((size_t)(b * 4096 + kv0 + it * 16 + kr_)) * 128 + ksl * 8];
        for (int it = 0; it < 4; ++it)
            vReg[it] = *(const bf16x8*)&vTw[((size_t)(b * 128 + it * 32 + vd_)) * 4096 + kv0 + vsl * 8];
    };

    issue(kt0);
    for (int kt = kt0; kt < kt1; ++kt) {
        __syncthreads();                          // prev-tile readers done
        for (int it = 0; it < 4; ++it) {
            int r = it * 16 + kr_;
            *(bf16x8*)((char*)Kl + r * 256 + ((ksl * 16) ^ ((r & 7) << 4))) = kReg[it];
        }
        for (int it = 0; it < 4; ++it) {
            int d = it * 32 + vd_;
            *(bf16x8*)((char*)Vl + d * 128 + ((vsl * 16) ^ ((d & 7) << 4))) = vReg[it];
        }
        __syncthreads();                          // tile visible
        if (kt + 1 < kt1) issue(kt + 1);          // hide under compute

        // S = Q K^T
        f32x4 s[4];
        __builtin_amdgcn_s_setprio(1);
        for (int ni = 0; ni < 4; ++ni) {
            s[ni] = (f32x4){0.f, 0.f, 0.f, 0.f};
            int kr = ni * 16 + l15;
            int sw = (kr & 7) << 4;
            for (int cc = 0; cc < 4; ++cc) {
                bf16x8 bk = *(bf16x8*)((char*)Kl + kr * 256 + ((lh * 16 + cc * 64) ^ sw));
                s[ni] = __builtin_amdgcn_mfma_f32_16x16x32_bf16(qa[cc], bk, s[ni], 0, 0, 0);
            }
        }
        __builtin_amdgcn_s_setprio(0);

        const bool diag = (kt == qt);
        for (int ni = 0; ni < 4; ++ni)
            for (int i = 0; i < 4; ++i) {
                float v = s[ni][i] * 0.03125f;      // C^-0.5 = 1024^-0.5
                bool masked = diag && (ni * 16 + l15 > w * 16 + lh * 4 + i);
                s[ni][i] = masked ? -INFINITY : v;
            }
        // online softmax; rows live on 16-lane groups (row = lh*4+i)
        float sc[4];
        for (int i = 0; i < 4; ++i) {
            float mx = fmaxf(fmaxf(s[0][i], s[1][i]), fmaxf(s[2][i], s[3][i]));
            for (int msk = 1; msk < 16; msk <<= 1) mx = fmaxf(mx, __shfl_xor(mx, msk));
            float mn = fmaxf(m_[i], mx);
            float e = __expf(m_[i] - mn);
            m_[i] = mn;
            float rs = 0.f;
            for (int ni = 0; ni < 4; ++ni) {
                float p = __expf(s[ni][i] - mn);
                s[ni][i] = p; rs += p;
            }
            for (int msk = 1; msk < 16; msk <<= 1) rs += __shfl_xor(rs, msk);
            ls[i] = ls[i] * e + rs;
            sc[i] = e;
        }
        for (int nd = 0; nd < 8; ++nd) {
            f32x4 t = o[nd];
            t[0] *= sc[0]; t[1] *= sc[1]; t[2] *= sc[2]; t[3] *= sc[3];
            o[nd] = t;
        }
        // P (C-layout) -> LDS (row-major, +8 pad), wave-local
        for (int ni = 0; ni < 4; ++ni)
            for (int i = 0; i < 4; ++i)
                Pl[w][(lh * 4 + i) * 72 + ni * 16 + l15] = f2bf(s[ni][i]);
        bf16x8 pa[2];
        for (int kc = 0; kc < 2; ++kc)
            pa[kc] = *(bf16x8*)&Pl[w][l15 * 72 + kc * 32 + lh * 8];
        __builtin_amdgcn_s_setprio(1);
        for (int nd = 0; nd < 8; ++nd) {
            int dr = nd * 16 + l15;
            int sw = (dr & 7) << 4;
            for (int kc = 0; kc < 2; ++kc) {
                bf16x8 bv = *(bf16x8*)((char*)Vl + dr * 128 + ((lh * 16 + kc * 64) ^ sw));
                o[nd] = __builtin_amdgcn_mfma_f32_16x16x32_bf16(pa[kc], bv, o[nd], 0, 0, 0);
            }
        }
        __builtin_amdgcn_s_setprio(0);
    }

    // epilogue: unnormalized partial O (bf16) + m,l (f32), compact slot
    const int slot = b * 288 + cid;
    unsigned short* po = pO + (size_t)slot * 8192;
    for (int nd = 0; nd < 8; ++nd)
        for (int i = 0; i < 4; ++i)
            po[(w * 16 + lh * 4 + i) * 128 + nd * 16 + l15] = f2bf(o[nd][i]);
    if (l15 == 0) {
        float* pml = pML + (size_t)slot * 128;
        for (int i = 0; i < 4; ++i) {
            int row = w * 16 + lh * 4 + i;
            pml[row * 2]     = m_[i];
            pml[row * 2 + 1] = ls[i];
        }
    }
}

// ---------------- Kernel 4: combine partials (8 outputs/thread) ------------
__global__ __launch_bounds__(256) void combine_kernel(
        const unsigned short* __restrict__ pO, const float* __restrict__ pML,
        float* __restrict__ out) {
    int idx = blockIdx.x * 256 + threadIdx.x;     // B*T*16 = 262144 threads
    int row = idx >> 4, d8 = (idx & 15) * 8;
    int b = row >> 12, t = row & 4095;
    int qt = t >> 6, rowin = t & 63;
    int j = qt >> 3;
    int nch = j + 1;
    int base = b * 288 + 4 * j * (j + 1) + (qt - 8 * j) * (j + 1);

    float M = -INFINITY;
    for (int cc = 0; cc < nch; ++cc)
        M = fmaxf(M, pML[(size_t)(base + cc) * 128 + rowin * 2]);
    float den = 0.f;
    float num[8] = {0.f, 0.f, 0.f, 0.f, 0.f, 0.f, 0.f, 0.f};
    for (int cc = 0; cc < nch; ++cc) {
        const float* pml = &pML[(size_t)(base + cc) * 128 + rowin * 2];
        float wgt = __expf(pml[0] - M);
        den += wgt * pml[1];
        bf16x8 ov = *(const bf16x8*)&pO[(size_t)(base + cc) * 8192 + rowin * 128 + d8];
        for (int u = 0; u < 8; ++u)
            num[u] += wgt * bf2f((unsigned short)ov[u]);
    }
    float inv = 1.f / den;
    for (int u = 0; u < 8; ++u)
        out[(size_t)row * 128 + d8 + u] = num[u] * inv;
}

// ---------------------------------------------------------------------------
extern "C" void kernel_launch(void* const* d_in, const int* in_sizes, int n_in,
                              void* d_out, int out_size, void* d_ws, size_t ws_size,
                              hipStream_t stream) {
    const float* x  = (const float*)d_in[0];
    const float* Wk = (const float*)d_in[1];
    const float* Wq = (const float*)d_in[2];
    const float* Wv = (const float*)d_in[3];
    float* out = (float*)d_out;

    // ws layout (bytes):
    //   WbT 786432 | k 4194304 | q 4194304 | vT 4194304
    //   pO 1152*16384 = 18874368 | pML 1152*512 = 589824   (total ~32.8 MB)
    char* ws = (char*)d_ws;
    unsigned short* WbT = (unsigned short*)(ws);
    unsigned short* kw  = (unsigned short*)(ws + 786432);
    unsigned short* qw  = (unsigned short*)(ws + 786432 + 4194304);
    unsigned short* vTw = (unsigned short*)(ws + 786432 + 2 * 4194304);
    unsigned short* pO  = (unsigned short*)(ws + 786432 + 3 * 4194304);
    float*          pML = (float*)(ws + 786432 + 3 * 4194304 + 18874368);

    wconv_kernel<<<1536, 256, 0, stream>>>(Wk, Wq, Wv, WbT);
    qkv_gemm_kernel<<<256, 512, 0, stream>>>(x, WbT, kw, qw, vTw);
    attn_kernel<<<dim3(288, 4), 256, 0, stream>>>(kw, qw, vTw, pO, pML);
    combine_kernel<<<1024, 256, 0, stream>>>(pO, pML, out);
}